// Round 15
// baseline (110.561 us; speedup 1.0000x reference)
//
#include <hip/hip_runtime.h>
#include <hip/hip_bf16.h>

#define N_SOURCE   100000
#define N_TARGET   4096
#define SOURCE_DIM 512
#define EMBED_DIM  32
#define TARGET_DIM 16
#define NTILES     ((N_SOURCE + 15) / 16)   // 6250 row-tiles of 16 (exact)

typedef __attribute__((ext_vector_type(8))) short short8;   // 8 bf16 (4 VGPR)
typedef __attribute__((ext_vector_type(4))) float f32x4;    // MFMA accumulator

static __device__ __forceinline__ ushort f2bf(float f) {
    __hip_bfloat16 h = __float2bfloat16(f);   // RNE
    return *(ushort*)&h;
}

// ---------------------------------------------------------------------------
// Kernel 1 (FUSED): y = bf16( (A @ (embed@weight)) / xnorm ) via MFMA.
// vs round 14: the separate k_embed_weight kernel is gone — each block
// computes its B tile in-kernel (weight column in 32 VGPRs, embed rows
// broadcast from global/L2). B math is bit-identical to the old kernel
// (f32 FMA, j ascending, RNE f2bf) so numerics are unchanged.
// Order: A-tile prefetch issues FIRST (32 dwordx4/lane); B-compute VALU
// (~1300 instr/thread incl loads) fills memory-stall slots (VALUBusy was
// 5%); one barrier; consume (full-sector + lane-transpose, R11-proven).
// GEMM knob scan is closed: occupancy x2 flat, req/2 -8%, L3 flat, nt -13%,
// depth x4 flat -> ~44us is this access shape's service ceiling.
// ---------------------------------------------------------------------------
__global__ __launch_bounds__(256, 2)
void k_gemm_y(const float*  __restrict__ A,       // source_feat [N_SOURCE][512]
              const float*  __restrict__ xnorm,   // [N_SOURCE]
              const float*  __restrict__ embed,   // [512][32]
              const float*  __restrict__ weight,  // [32][16]
              ushort*       __restrict__ y) {     // [N_SOURCE][16] bf16
    __shared__ ushort Bl[SOURCE_DIM * TARGET_DIM];   // 16 KB, fragment-ordered
    int tid  = threadIdx.x;
    int wave = tid >> 6;
    int lane = tid & 63;
    int n    = lane & 15;     // C col / fragment row
    int g    = lane >> 4;     // k-group 0..3

    // ---- A-tile whole-tile prefetch: issue all 32 loads FIRST ----
    int tile  = blockIdx.x * 4 + wave;
    int tilec = tile < NTILES ? tile : NTILES - 1;   // clamp addresses only
    int row0  = tilec * 16;
    int lr = lane >> 2;              // row this lane loads (0..15)
    int q  = lane & 3;               // 16B slot within the 64B sector
    const float* Aload = A + (size_t)(row0 + lr) * SOURCE_DIM + q * 4;

    f32x4 buf[32];
    #pragma unroll
    for (int kk = 0; kk < 16; ++kk) {
        buf[2 * kk]     = *(const f32x4*)(Aload + kk * 32);       // sector 0
        buf[2 * kk + 1] = *(const f32x4*)(Aload + kk * 32 + 16);  // sector 1
    }

    // ---- fused B: M = embed @ weight, written in fragment order ----
    // thread's column nn = tid&15 is constant across its 4 chunks
    int nn = tid & 15;
    float wcol[EMBED_DIM];
    #pragma unroll
    for (int j = 0; j < EMBED_DIM; ++j)
        wcol[j] = weight[j * TARGET_DIM + nn];

    #pragma unroll
    for (int i = 0; i < 4; ++i) {
        int c  = tid + 256 * i;          // chunk 0..1023 = (kk*4+g)*16 + nn
        int kg = c >> 4;                 // kk*4+g
        int k0 = (kg >> 2) * 32 + (kg & 3) * 8;   // first of 8 k's
        uint d[4];
        #pragma unroll
        for (int p = 0; p < 4; ++p) {
            const float* e0 = embed + (size_t)(k0 + 2 * p)     * EMBED_DIM;
            const float* e1 = embed + (size_t)(k0 + 2 * p + 1) * EMBED_DIM;
            float s0 = 0.f, s1 = 0.f;
            #pragma unroll
            for (int j = 0; j < EMBED_DIM; ++j) {   // same order as old kernel
                s0 += e0[j] * wcol[j];
                s1 += e1[j] * wcol[j];
            }
            d[p] = (uint)f2bf(s0) | ((uint)f2bf(s1) << 16);
        }
        *(uint4*)&Bl[c * 8] = make_uint4(d[0], d[1], d[2], d[3]);
    }
    __syncthreads();                 // Bl visible; A-buf drained here anyway

    if (tile < NTILES) {
        // consumer-side exchange indices (fixed 16x4 lane transpose)
        int sA = (n << 2) | ((2 * g) & 3);       // src of float4 F=2g
        int sB = (n << 2) | ((2 * g + 1) & 3);   // src of float4 F=2g+1
        bool hi = g >= 2;                        // piece select (a0 vs a1)

        const ushort* Bll = Bl + lane * 8;       // +kk*512 ushorts per step

        f32x4 acc = {0.f, 0.f, 0.f, 0.f};
        #pragma unroll
        for (int kk = 0; kk < 16; ++kk) {
            f32x4 a0 = buf[2 * kk];
            f32x4 a1 = buf[2 * kk + 1];

            // pack to bf16 dwords (dword j = floats 2j,2j+1 of the float4)
            uint u00 = (uint)f2bf(a0[0]) | ((uint)f2bf(a0[1]) << 16);
            uint u01 = (uint)f2bf(a0[2]) | ((uint)f2bf(a0[3]) << 16);
            uint u10 = (uint)f2bf(a1[0]) | ((uint)f2bf(a1[1]) << 16);
            uint u11 = (uint)f2bf(a1[2]) | ((uint)f2bf(a1[3]) << 16);

            // pull the fragment dwords from the loader lanes
            uint e0 = (uint)__shfl((int)u00, sA);
            uint e1 = (uint)__shfl((int)u01, sA);
            uint e2 = (uint)__shfl((int)u00, sB);
            uint e3 = (uint)__shfl((int)u01, sB);
            uint f0 = (uint)__shfl((int)u10, sA);
            uint f1 = (uint)__shfl((int)u11, sA);
            uint f2 = (uint)__shfl((int)u10, sB);
            uint f3 = (uint)__shfl((int)u11, sB);

            union { short8 s; uint u[4]; } af;
            af.u[0] = hi ? f0 : e0;
            af.u[1] = hi ? f1 : e1;
            af.u[2] = hi ? f2 : e2;
            af.u[3] = hi ? f3 : e3;

            short8 bf = *(const short8*)(Bll + kk * 512);   // ds_read_b128
            acc = __builtin_amdgcn_mfma_f32_16x16x32_bf16(af.s, bf, acc, 0, 0, 0);
        }

        // epilogue: lane holds C[g*4 + r][n], r = 0..3
        int m0 = g * 4;
        float4 xn = *(const float4*)(xnorm + row0 + m0);   // 16B aligned
        const float xr[4] = {xn.x, xn.y, xn.z, xn.w};
        #pragma unroll
        for (int r = 0; r < 4; ++r)
            y[(size_t)(row0 + m0 + r) * TARGET_DIM + n] = f2bf(acc[r] / xr[r]);
    }
}

// ---------------------------------------------------------------------------
// Kernel 2 (exact round-6/8 version, measured 14.7 us): block per target,
// int4 index loads -> 4 independent uint4 gathers (ILP 4).
// ---------------------------------------------------------------------------
__global__ __launch_bounds__(256)
void k_gather_mean(const ushort* __restrict__ y,   // [N_SOURCE][16] bf16
                   const int*    __restrict__ src, // edge sources
                   const int*    __restrict__ rl,  // range_list [N_TARGET][2]
                   float* __restrict__ out) {      // [N_TARGET][16] f32
    int t     = blockIdx.x;
    int tid   = threadIdx.x;
    int start = rl[2 * t];
    int end   = rl[2 * t + 1];

    int slot = tid >> 1;          // 0..127
    int sub  = tid & 1;           // which 16B half of the 32B row

    float a[8];
    #pragma unroll
    for (int i = 0; i < 8; ++i) a[i] = 0.f;

    for (int base = start + slot * 4; base < end; base += 512) {
        int rem = end - base;     // >= 1 here
        int id[4];
        if (rem >= 4) {           // aligned: start%4==0 (range starts 800*t)
            int4 qd = *(const int4*)(src + base);
            id[0] = qd.x; id[1] = qd.y; id[2] = qd.z; id[3] = qd.w;
        } else {
            #pragma unroll
            for (int j = 0; j < 4; ++j) id[j] = (j < rem) ? src[base + j] : 0;
        }
        #pragma unroll
        for (int j = 0; j < 4; ++j) {
            if (j < rem) {
                uint4 v = *(const uint4*)(y + (size_t)id[j] * TARGET_DIM + sub * 8);
                const uint w[4] = {v.x, v.y, v.z, v.w};
                #pragma unroll
                for (int i = 0; i < 4; ++i) {
                    uint lo = w[i] << 16;
                    uint hiw = w[i] & 0xffff0000u;
                    a[2 * i]     += *(float*)&lo;
                    a[2 * i + 1] += *(float*)&hiw;
                }
            }
        }
    }

    // butterfly over slot bits within the wave (lane bits 1..5)
    #pragma unroll
    for (int m = 2; m <= 32; m <<= 1) {
        #pragma unroll
        for (int i = 0; i < 8; ++i) a[i] += __shfl_xor(a[i], m);
    }

    __shared__ float red[4][16];
    int wid  = tid >> 6;
    int lane = tid & 63;
    if (lane < 2) {               // lane0 = cols 0..7, lane1 = cols 8..15
        #pragma unroll
        for (int i = 0; i < 8; ++i) red[wid][lane * 8 + i] = a[i];
    }
    __syncthreads();

    if (tid < TARGET_DIM) {
        float s = red[0][tid] + red[1][tid] + red[2][tid] + red[3][tid];
        float deg = (float)(end - start);
        deg = deg > 1.f ? deg : 1.f;
        out[t * TARGET_DIM + tid] = s / deg;
    }
}

// ---------------------------------------------------------------------------
extern "C" void kernel_launch(void* const* d_in, const int* in_sizes, int n_in,
                              void* d_out, int out_size, void* d_ws, size_t ws_size,
                              hipStream_t stream) {
    const float* source_feat = (const float*)d_in[0];  // [100000][512]
    const float* embed       = (const float*)d_in[1];  // [512][32]
    const float* weight      = (const float*)d_in[2];  // [32][16]
    const int*   edge_src    = (const int*)d_in[3];    // edge_index[0][:]
    const int*   range_list  = (const int*)d_in[4];    // [4096][2]
    const float* x_norm      = (const float*)d_in[5];  // [100000]

    float*  out = (float*)d_out;
    ushort* y   = (ushort*)d_ws;                        // 3.2 MB bf16

    int nblk = (NTILES + 3) / 4;                        // 1563
    k_gemm_y<<<nblk, 256, 0, stream>>>(source_feat, x_norm, embed, weight, y);

    k_gather_mean<<<N_TARGET, 256, 0, stream>>>(y, edge_src, range_list, out);
}

// Round 16
// 61.503 us; speedup vs baseline: 1.7977x; 1.7977x over previous
//
#include <hip/hip_runtime.h>
#include <hip/hip_bf16.h>

#define N_SOURCE   100000
#define N_TARGET   4096
#define SOURCE_DIM 512
#define EMBED_DIM  32
#define TARGET_DIM 16
#define NTILES     ((N_SOURCE + 15) / 16)   // 6250 row-tiles of 16 (exact)

typedef __attribute__((ext_vector_type(8))) short short8;   // 8 bf16 (4 VGPR)
typedef __attribute__((ext_vector_type(4))) float f32x4;    // MFMA accumulator

static __device__ __forceinline__ ushort f2bf(float f) {
    __hip_bfloat16 h = __float2bfloat16(f);   // RNE
    return *(ushort*)&h;
}

// ---------------------------------------------------------------------------
// Kernel 0: Mt = bf16( (embed @ weight)^T )   [16][512]  (folds both GEMMs)
// (restored — R15 fusion spilled: VGPR 76 with 128-VGPR buf => scratch)
// ---------------------------------------------------------------------------
__global__ __launch_bounds__(256)
void k_embed_weight(const float* __restrict__ embed,   // [512][32]
                    const float* __restrict__ weight,  // [32][16]
                    ushort* __restrict__ Mt) {         // [16][512] bf16
    __shared__ float wlds[EMBED_DIM * TARGET_DIM];
    int tid = threadIdx.x;
    for (int i = tid; i < EMBED_DIM * TARGET_DIM; i += 256)
        wlds[i] = weight[i];
    __syncthreads();

    int idx = blockIdx.x * 256 + tid;                  // 0..8191
    if (idx < SOURCE_DIM * TARGET_DIM) {
        int k = idx >> 4;        // K index
        int o = idx & 15;        // output col
        float s = 0.f;
        #pragma unroll
        for (int j = 0; j < EMBED_DIM; ++j)
            s += embed[k * EMBED_DIM + j] * wlds[j * TARGET_DIM + o];
        Mt[o * SOURCE_DIM + k] = f2bf(s);              // transposed store
    }
}

// ---------------------------------------------------------------------------
// Kernel 1: y = bf16( (A @ M) / xnorm ) via MFMA.
// NEW: COPY-SHAPED A loads. Load j (j=0..31): row j/2, half j&1 — 64 lanes
// read 1KB CONTIGUOUS (8 sequential 128B lines/instr, the m13 copy shape)
// vs all prior variants' 16-scattered-lines/instr (17 cy/line measured vs
// copy's 1.6). Data lands via bf16-cvt + swizzled ds_write_b64 into a
// per-wave fragment-ordered A-LDS; consume is ds_read_b128 (linear-in-lane,
// conflict-free) + MFMA — no shfl, no cvt in the hot loop.
// Swizzle: phys = logical ^ (((logical>>8)&7)<<4)  (hand-verified 3 pairs).
// LDS: Bl 16KB + 4x16KB A = 80KB dynamic -> 2 blocks/CU.
// ---------------------------------------------------------------------------
__global__ __launch_bounds__(256, 2)
void k_gemm_y(const float*  __restrict__ A,      // source_feat [N_SOURCE][512]
              const float*  __restrict__ xnorm,  // [N_SOURCE]
              const ushort* __restrict__ Mt,     // [16][512] bf16
              ushort*       __restrict__ y) {    // [N_SOURCE][16] bf16
    extern __shared__ ushort smem[];             // 80 KB dynamic
    ushort* Bl  = smem;                          // 8192 ushorts = 16 KB
    int tid  = threadIdx.x;
    int wave = tid >> 6;
    int lane = tid & 63;
    ushort* AlW = smem + 8192 + wave * 8192;     // this wave's 16 KB A tile

    // ---- stage B in fragment order (R8-proven, conflict-free) ----
    #pragma unroll
    for (int i = 0; i < 4; ++i) {
        int c  = tid + 256 * i;          // 0..1023
        int nn = c & 15;
        int kg = c >> 4;                 // kk*4+g
        int kk = kg >> 2;
        int gg = kg & 3;
        *(uint4*)&Bl[c * 8] =
            *(const uint4*)(Mt + nn * SOURCE_DIM + kk * 32 + gg * 8);
    }

    // ---- stage A: 32 copy-shaped loads -> cvt -> swizzled ds_write_b64 ----
    int tile  = blockIdx.x * 4 + wave;
    int tilec = tile < NTILES ? tile : NTILES - 1;   // clamp addrs only
    int row0  = tilec * 16;

    // lane-constant parts of the write address:
    // logical = h*8192 + (l>>3)*1024 + ((l>>1)&3)*256 + r*16 + (l&1)*8
    // swizzle x = (4*(l>>3) + ((l>>1)&3)) & 7  (lane-const)
    int laneConst = ((lane >> 3) << 10) | (((lane >> 1) & 3) << 8) | ((lane & 1) << 3);
    int xl        = ((laneConst >> 8) & 7);

    #pragma unroll
    for (int j = 0; j < 32; ++j) {
        int r = j >> 1, h = j & 1;
        f32x4 v = *(const f32x4*)(A + (size_t)(row0 + r) * SOURCE_DIM
                                    + h * 256 + lane * 4);
        uint d0 = (uint)f2bf(v[0]) | ((uint)f2bf(v[1]) << 16);
        uint d1 = (uint)f2bf(v[2]) | ((uint)f2bf(v[3]) << 16);
        int phys = (h << 13) + (laneConst & ~0xF8) + (laneConst & 0x700)
                 + (laneConst & 0x7C00)            // = laneConst, kept simple:
                 ;
        // phys = laneConst + h*8192 + ((r ^ xl) << 4)
        phys = laneConst + (h << 13) + ((r ^ xl) << 4);
        *(uint2*)((char*)AlW + phys) = make_uint2(d0, d1);
    }

    __syncthreads();   // Bl visible (A writes are same-wave, covered anyway)

    if (tile < NTILES) {
        int n = lane & 15;     // C col / A row
        int g = lane >> 4;     // k-group 0..3
        const ushort* Bll = Bl + lane * 8;       // +kk*512 ushorts per step

        f32x4 acc = {0.f, 0.f, 0.f, 0.f};
        #pragma unroll
        for (int kk = 0; kk < 16; ++kk) {
            // A fragment: logical chunk = kk*64 + lane; swz lands on lane&7
            int xr = (4 * kk + (lane >> 4)) & 7;
            const short8 af = *(const short8*)
                ((char*)AlW + kk * 1024 + ((lane ^ xr) << 4));
            const short8 bf = *(const short8*)(Bll + kk * 512);
            acc = __builtin_amdgcn_mfma_f32_16x16x32_bf16(af, bf, acc, 0, 0, 0);
        }

        // epilogue: lane holds C[g*4 + r][n], r = 0..3
        int m0 = g * 4;
        float4 xn = *(const float4*)(xnorm + row0 + m0);   // 16B aligned
        const float xr4[4] = {xn.x, xn.y, xn.z, xn.w};
        #pragma unroll
        for (int r = 0; r < 4; ++r)
            y[(size_t)(row0 + m0 + r) * TARGET_DIM + n] = f2bf(acc[r] / xr4[r]);
    }
}

// ---------------------------------------------------------------------------
// Kernel 2 (exact round-6/8 version, measured 14.7 us): block per target,
// int4 index loads -> 4 independent uint4 gathers (ILP 4).
// ---------------------------------------------------------------------------
__global__ __launch_bounds__(256)
void k_gather_mean(const ushort* __restrict__ y,   // [N_SOURCE][16] bf16
                   const int*    __restrict__ src, // edge sources
                   const int*    __restrict__ rl,  // range_list [N_TARGET][2]
                   float* __restrict__ out) {      // [N_TARGET][16] f32
    int t     = blockIdx.x;
    int tid   = threadIdx.x;
    int start = rl[2 * t];
    int end   = rl[2 * t + 1];

    int slot = tid >> 1;          // 0..127
    int sub  = tid & 1;           // which 16B half of the 32B row

    float a[8];
    #pragma unroll
    for (int i = 0; i < 8; ++i) a[i] = 0.f;

    for (int base = start + slot * 4; base < end; base += 512) {
        int rem = end - base;     // >= 1 here
        int id[4];
        if (rem >= 4) {           // aligned: start%4==0 (range starts 800*t)
            int4 qd = *(const int4*)(src + base);
            id[0] = qd.x; id[1] = qd.y; id[2] = qd.z; id[3] = qd.w;
        } else {
            #pragma unroll
            for (int j = 0; j < 4; ++j) id[j] = (j < rem) ? src[base + j] : 0;
        }
        #pragma unroll
        for (int j = 0; j < 4; ++j) {
            if (j < rem) {
                uint4 v = *(const uint4*)(y + (size_t)id[j] * TARGET_DIM + sub * 8);
                const uint w[4] = {v.x, v.y, v.z, v.w};
                #pragma unroll
                for (int i = 0; i < 4; ++i) {
                    uint lo = w[i] << 16;
                    uint hiw = w[i] & 0xffff0000u;
                    a[2 * i]     += *(float*)&lo;
                    a[2 * i + 1] += *(float*)&hiw;
                }
            }
        }
    }

    // butterfly over slot bits within the wave (lane bits 1..5)
    #pragma unroll
    for (int m = 2; m <= 32; m <<= 1) {
        #pragma unroll
        for (int i = 0; i < 8; ++i) a[i] += __shfl_xor(a[i], m);
    }

    __shared__ float red[4][16];
    int wid  = tid >> 6;
    int lane = tid & 63;
    if (lane < 2) {               // lane0 = cols 0..7, lane1 = cols 8..15
        #pragma unroll
        for (int i = 0; i < 8; ++i) red[wid][lane * 8 + i] = a[i];
    }
    __syncthreads();

    if (tid < TARGET_DIM) {
        float s = red[0][tid] + red[1][tid] + red[2][tid] + red[3][tid];
        float deg = (float)(end - start);
        deg = deg > 1.f ? deg : 1.f;
        out[t * TARGET_DIM + tid] = s / deg;
    }
}

// ---------------------------------------------------------------------------
extern "C" void kernel_launch(void* const* d_in, const int* in_sizes, int n_in,
                              void* d_out, int out_size, void* d_ws, size_t ws_size,
                              hipStream_t stream) {
    const float* source_feat = (const float*)d_in[0];  // [100000][512]
    const float* embed       = (const float*)d_in[1];  // [512][32]
    const float* weight      = (const float*)d_in[2];  // [32][16]
    const int*   edge_src    = (const int*)d_in[3];    // edge_index[0][:]
    const int*   range_list  = (const int*)d_in[4];    // [4096][2]
    const float* x_norm      = (const float*)d_in[5];  // [100000]

    float*  out = (float*)d_out;
    ushort* Mt  = (ushort*)d_ws;                        // 16 KB bf16 [16][512]
    ushort* y   = (ushort*)((char*)d_ws + 16384);       // 3.2 MB bf16

    k_embed_weight<<<32, 256, 0, stream>>>(embed, weight, Mt);

    int nblk = (NTILES + 3) / 4;                        // 1563
    k_gemm_y<<<nblk, 256, 81920, stream>>>(source_feat, x_norm, Mt, y);

    k_gather_mean<<<N_TARGET, 256, 0, stream>>>(y, edge_src, range_list, out);
}